// Round 4
// baseline (320.159 us; speedup 1.0000x reference)
//
#include <hip/hip_runtime.h>
#include <math.h>

#define B_ 256
#define K_ 256
#define H_ 128
#define I_ 64
#define O_ 64
#define NU 6
#define BP 128   // particles per block in prop kernel

// ---------------- propagation kernel ----------------
// grid: (B*K)/BP blocks of 256 threads. Each block: 128 particles of one batch.
// LDS: Wh[128][128] (64KB) + sT[k][m] (64KB) + xwx/gsd (1KB) = ~129KB -> 1 block/CU.
// Thread tile: 8 particles x 8 state dims (8m x 8j), 2 FLOP/LDS-byte.
__global__ __launch_bounds__(256) void prop_kernel(
    const float* __restrict__ x,          // [B,I]
    const float* __restrict__ particles,  // [B*K,H]
    const float* __restrict__ noise,      // [B*K,NU,H]
    const float* __restrict__ Wx,         // [I,H]
    const float* __restrict__ Wh,         // [H,H]
    const float* __restrict__ bvec,       // [H]
    const float* __restrict__ log_sigma,  // [H]
    float* __restrict__ p_out)            // [B*K,H]
{
  __shared__ __align__(16) float wh[H_][H_];
  __shared__ __align__(16) float sT[H_][BP];   // [k][m]
  __shared__ float xwx[H_];
  __shared__ float gsd[H_];

  const int tid = threadIdx.x;
  const int bk0 = blockIdx.x * BP;
  const int b   = bk0 >> 8;   // /K_ ; BP=128 divides K=256 evenly

  // stage Wh into LDS (16 float4 per thread)
  {
    const float4* src = (const float4*)Wh;
    float4* dst = (float4*)&wh[0][0];
#pragma unroll
    for (int i = 0; i < (H_*H_/4)/256; ++i)
      dst[tid + i*256] = src[tid + i*256];
  }
  // xWx + b (per-batch, recomputed per block: 8K FMA, negligible) and g*sqrt_dt
  if (tid < H_) {
    float acc = bvec[tid];
#pragma unroll 8
    for (int i = 0; i < I_; ++i) acc = fmaf(x[b*I_ + i], Wx[i*H_ + tid], acc);
    xwx[tid] = acc;
    gsd[tid] = log1pf(expf(log_sigma[tid])) * sqrtf(1.0f/6.0f);
  }

  const int tj = tid & 15, tm = tid >> 4;
  const int j0 = tj * 8, m0 = tm * 8;

  // load this thread's 8x8 state tile into registers, and into sT (transposed)
  float s_reg[8][8];
#pragma unroll
  for (int mm = 0; mm < 8; ++mm) {
    const float* row = &particles[(size_t)(bk0 + m0 + mm) * H_ + j0];
    float4 a = *(const float4*)row;
    float4 c = *(const float4*)(row + 4);
    s_reg[mm][0]=a.x; s_reg[mm][1]=a.y; s_reg[mm][2]=a.z; s_reg[mm][3]=a.w;
    s_reg[mm][4]=c.x; s_reg[mm][5]=c.y; s_reg[mm][6]=c.z; s_reg[mm][7]=c.w;
#pragma unroll
    for (int jj = 0; jj < 8; ++jj) sT[j0+jj][m0+mm] = s_reg[mm][jj];
  }
  __syncthreads();

  const float dt = 1.0f/6.0f;
  for (int n = 0; n < NU; ++n) {
    float acc[8][8];
#pragma unroll
    for (int mm=0;mm<8;++mm)
#pragma unroll
      for (int jj=0;jj<8;++jj) acc[mm][jj]=0.f;

    // t = s @ Wh : outer-product accumulation over k
#pragma unroll 8
    for (int k = 0; k < H_; ++k) {
      float4 sa = *(const float4*)&sT[k][m0];
      float4 sb = *(const float4*)&sT[k][m0+4];
      float4 wa = *(const float4*)&wh[k][j0];
      float4 wb = *(const float4*)&wh[k][j0+4];
      float sv[8]={sa.x,sa.y,sa.z,sa.w,sb.x,sb.y,sb.z,sb.w};
      float wv[8]={wa.x,wa.y,wa.z,wa.w,wb.x,wb.y,wb.z,wb.w};
#pragma unroll
      for (int mm=0;mm<8;++mm)
#pragma unroll
        for (int jj=0;jj<8;++jj)
          acc[mm][jj] = fmaf(sv[mm], wv[jj], acc[mm][jj]);
    }

    // EM update: s += (tanh(xwx + sWh) - s)*dt + g*sqrt_dt*eps
#pragma unroll
    for (int mm = 0; mm < 8; ++mm) {
      const float* nrow = &noise[((size_t)(bk0+m0+mm)*NU + n)*H_ + j0];
      float4 ea = *(const float4*)nrow;
      float4 eb = *(const float4*)(nrow + 4);
      float ev[8]={ea.x,ea.y,ea.z,ea.w,eb.x,eb.y,eb.z,eb.w};
#pragma unroll
      for (int jj=0;jj<8;++jj){
        float t = tanhf(xwx[j0+jj] + acc[mm][jj]);
        float s = s_reg[mm][jj];
        s_reg[mm][jj] = s + (t - s)*dt + gsd[j0+jj]*ev[jj];
      }
    }
    __syncthreads();   // all GEMM reads of sT complete
#pragma unroll
    for (int mm=0;mm<8;++mm)
#pragma unroll
      for (int jj=0;jj<8;++jj)
        sT[j0+jj][m0+mm] = s_reg[mm][jj];
    __syncthreads();
  }

  // write new particles
#pragma unroll
  for (int mm = 0; mm < 8; ++mm) {
    float* row = &p_out[(size_t)(bk0+m0+mm)*H_ + j0];
    float4 a = {s_reg[mm][0],s_reg[mm][1],s_reg[mm][2],s_reg[mm][3]};
    float4 c = {s_reg[mm][4],s_reg[mm][5],s_reg[mm][6],s_reg[mm][7]};
    *(float4*)row = a;
    *(float4*)(row+4) = c;
  }
}

// ---------------- resampling + weighted output kernel ----------------
__device__ __forceinline__ float blk_max(float v, float* red, int k){
  red[k]=v; __syncthreads();
  for (int off=128; off>0; off>>=1){ if (k<off) red[k]=fmaxf(red[k],red[k+off]); __syncthreads(); }
  float r = red[0]; __syncthreads(); return r;
}
__device__ __forceinline__ float blk_sum(float v, float* red, int k){
  red[k]=v; __syncthreads();
  for (int off=128; off>0; off>>=1){ if (k<off) red[k]+=red[k+off]; __syncthreads(); }
  float r = red[0]; __syncthreads(); return r;
}

// one block per batch, 256 threads = K particles
__global__ __launch_bounds__(256) void finish_kernel(
  const float* __restrict__ log_weights,   // [B,K]
  const float* __restrict__ resample_u,    // [B,K]
  const float* __restrict__ W_out,         // [H,O]
  const float* __restrict__ b_out,         // [O]
  const float* __restrict__ alpha_logit,   // [1]
  float* __restrict__ p,                   // [B*K,H] new particles (in d_out; maybe overwritten)
  float* __restrict__ out0,                // [B,O]
  float* __restrict__ lw_out)              // [B,K]
{
  const int b = blockIdx.x, k = threadIdx.x;
  __shared__ float red[K_];
  __shared__ float lw[K_], qv[K_], cdf[K_], wt[K_];
  __shared__ float ws_h[H_];

  // normalized log-weights
  float lwk = log_weights[b*K_ + k];
  float mx  = blk_max(lwk, red, k);
  float se  = blk_sum(expf(lwk - mx), red, k);
  float lse = mx + logf(se);
  float lwn = lwk - lse;
  lw[k] = lwn;
  float w = expf(lwn);
  float sw2 = blk_sum(w*w, red, k);     // syncs make lw[] visible
  float ess = 1.0f / sw2;

  float alpha = 1.0f/(1.0f + expf(-alpha_logit[0]));
  float qk = alpha*w + (1.0f-alpha)*(1.0f/K_);
  qv[k] = qk;
  cdf[k] = qk; __syncthreads();
  // inclusive scan (Hillis-Steele)
  for (int off=1; off<K_; off<<=1){
    float add = (k>=off)? cdf[k-off] : 0.0f;
    __syncthreads();
    cdf[k] += add;
    __syncthreads();
  }
  // searchsorted left: first i with cdf[i] >= u
  float u = resample_u[b*K_ + k];
  int lo=0, cnt=K_;
  while (cnt>0){ int st=cnt>>1; if (cdf[lo+st] < u){ lo += st+1; cnt -= st+1; } else cnt = st; }
  int idx = min(lo, K_-1);

  float lr  = lw[idx] - logf(qv[idx]);
  float mx2 = blk_max(lr, red, k);
  float se2 = blk_sum(expf(lr-mx2), red, k);
  float lrn = lr - (mx2 + logf(se2));

  bool need = ess < 0.5f * K_;          // uniform across block
  float flw = need ? lrn : lwn;
  lw_out[b*K_ + k] = flw;

  float mx3 = blk_max(flw, red, k);
  float se3 = blk_sum(expf(flw-mx3), red, k);
  float wk  = expf(flw - (mx3 + logf(se3)));
  wt[k] = wk;
  float sumw = blk_sum(wk, red, k);     // syncs make wt[] visible

  // weighted particle average: ws_h[h] = sum_k wt[k]*p[b,k,h]
  int h = k & (H_-1), half = k >> 7;
  float part = 0.f;
  const float* pb = &p[(size_t)b*K_*H_];
  for (int kk = half*128; kk < half*128 + 128; ++kk)
    part = fmaf(wt[kk], pb[(size_t)kk*H_ + h], part);
  red[k] = part; __syncthreads();
  if (k < H_) ws_h[k] = red[k] + red[k+H_];
  __syncthreads();

  // output = ws_h @ W_out + sum(w)*b_out
  if (k < O_) {
    float acc = sumw * b_out[k];
#pragma unroll 8
    for (int hh = 0; hh < H_; ++hh) acc = fmaf(ws_h[hh], W_out[hh*O_ + k], acc);
    out0[b*O_ + k] = acc;
  }

  // in-place gather if resampling triggers (chunked read->sync->write to avoid hazard)
  if (need) {
    const float* src = &p[((size_t)b*K_ + idx)*H_];
    float* dstp      = &p[((size_t)b*K_ + k  )*H_];
    float tmp[16];
    for (int c = 0; c < H_; c += 16){
#pragma unroll
      for (int t=0;t<16;++t) tmp[t]=src[c+t];
      __syncthreads();
#pragma unroll
      for (int t=0;t<16;++t) dstp[c+t]=tmp[t];
      __syncthreads();
    }
  }
}

extern "C" void kernel_launch(void* const* d_in, const int* in_sizes, int n_in,
                              void* d_out, int out_size, void* d_ws, size_t ws_size,
                              hipStream_t stream) {
  const float* x           = (const float*)d_in[0];
  const float* particles   = (const float*)d_in[1];
  const float* log_weights = (const float*)d_in[2];
  const float* noise       = (const float*)d_in[3];
  const float* resample_u  = (const float*)d_in[4];
  const float* Wx          = (const float*)d_in[5];
  const float* Wh          = (const float*)d_in[6];
  const float* bvec        = (const float*)d_in[7];
  const float* log_sigma   = (const float*)d_in[8];
  const float* W_out       = (const float*)d_in[9];
  const float* b_out       = (const float*)d_in[10];
  const float* alpha_logit = (const float*)d_in[11];

  float* out0   = (float*)d_out;
  float* p_out  = out0 + B_*O_;
  float* lw_out = p_out + (size_t)B_*K_*H_;

  prop_kernel<<<(B_*K_)/BP, 256, 0, stream>>>(
      x, particles, noise, Wx, Wh, bvec, log_sigma, p_out);
  finish_kernel<<<B_, 256, 0, stream>>>(
      log_weights, resample_u, W_out, b_out, alpha_logit, p_out, out0, lw_out);
}

// Round 5
// 192.400 us; speedup vs baseline: 1.6640x; 1.6640x over previous
//
#include <hip/hip_runtime.h>
#include <math.h>

#define B_ 256
#define K_ 256
#define H_ 128
#define I_ 64
#define O_ 64
#define NU 6
#define BP 64    // particles per block (4 waves x 16)
#define MW 16    // particles per wave

typedef short bf16x8 __attribute__((ext_vector_type(8)));  // 8 bf16 in 4 VGPRs
typedef float f32x4  __attribute__((ext_vector_type(4)));

// RNE float->bf16 bits (portable, ~4 VALU ops)
__device__ __forceinline__ unsigned short f2bf(float f) {
  unsigned int u = __builtin_bit_cast(unsigned int, f);
  unsigned int r = (u + 0x7FFFu + ((u >> 16) & 1u)) >> 16;
  return (unsigned short)r;
}

// XOR-swizzled byte offset in a [rows][128] bf16 tile (row stride 256B).
// Spreads the 16-row column-slice reads across 16 distinct 16B slots (T2).
__device__ __forceinline__ unsigned int swz(unsigned int row, unsigned int col) {
  return (row * 256u + col * 2u) ^ ((row & 15u) << 4);
}

__device__ __forceinline__ float tanh_fast(float x) {
  // tanh(x) = 1 - 2/(e^{2x}+1); exact limits at +-inf, ~1e-6 rel err
  float e = __expf(2.0f * x);
  return 1.0f - 2.0f * __builtin_amdgcn_rcpf(e + 1.0f);
}

// ---------------- propagation kernel (bf16 MFMA) ----------------
// grid: (B*K)/BP = 1024 blocks x 256 threads. LDS ~49.3KB -> 3 blocks/CU.
// Per wave: 16 particles. s master in fp32 regs (D-layout), GEMM operands bf16.
__global__ __launch_bounds__(256, 2) void prop_kernel(
    const float* __restrict__ x,          // [B,I]
    const float* __restrict__ particles,  // [B*K,H]
    const float* __restrict__ noise,      // [B*K,NU,H]
    const float* __restrict__ Wx,         // [I,H]
    const float* __restrict__ Wh,         // [H,H]
    const float* __restrict__ bvec,       // [H]
    const float* __restrict__ log_sigma,  // [H]
    float* __restrict__ p_out)            // [B*K,H]
{
  __shared__ __align__(16) unsigned short whT[H_ * H_]; // bf16 Wh^T [c][k], swizzled, 32KB
  __shared__ __align__(16) unsigned short sS[BP * H_];  // bf16 state [p][d], swizzled, 16KB
  __shared__ float xwx[H_];
  __shared__ float gsd[H_];

  const int tid  = threadIdx.x;
  const int lane = tid & 63;
  const int wave = tid >> 6;
  const int bk0  = blockIdx.x * BP;
  const int b    = bk0 >> 8;          // /K_

  // ---- stage Wh^T as bf16 (swizzled) ----
#pragma unroll
  for (int it = 0; it < 16; ++it) {
    int idx = tid + it * 256;         // float4 index over Wh [k][c]
    int k   = idx >> 5;               // 32 float4 per row
    int c0  = (idx & 31) * 4;
    float4 v = ((const float4*)Wh)[idx];
    float vv[4] = {v.x, v.y, v.z, v.w};
#pragma unroll
    for (int e = 0; e < 4; ++e)
      *(unsigned short*)((char*)whT + swz(c0 + e, k)) = f2bf(vv[e]);
  }
  // ---- xWx + b and g*sqrt(dt) ----
  if (tid < H_) {
    float acc = bvec[tid];
#pragma unroll 8
    for (int i = 0; i < I_; ++i) acc = fmaf(x[b * I_ + i], Wx[i * H_ + tid], acc);
    xwx[tid] = acc;
    gsd[tid] = log1pf(expf(log_sigma[tid])) * sqrtf(1.0f / 6.0f);
  }
  __syncthreads();

  const int lr   = lane & 15;          // col within 16-tile / A-row selector
  const int lg   = lane >> 4;          // 0..3
  const int prow = wave * MW + lg * 4; // base particle row (+r), this lane's D rows

  // per-lane loop-invariant vectors
  float xwx_r[8], gsd_r[8];
#pragma unroll
  for (int ct = 0; ct < 8; ++ct) { xwx_r[ct] = xwx[ct * 16 + lr]; gsd_r[ct] = gsd[ct * 16 + lr]; }

  // fp32 master state in D layout: s[ct][r] = S[prow+r][ct*16+lr]
  float s[8][4];
#pragma unroll
  for (int ct = 0; ct < 8; ++ct)
#pragma unroll
    for (int r = 0; r < 4; ++r)
      s[ct][r] = particles[(size_t)(bk0 + prow + r) * H_ + ct * 16 + lr];

  const float dt = 1.0f / 6.0f;
#pragma unroll 1
  for (int n = 0; n < NU; ++n) {
    // 1) write s -> sS in bf16 (own wave's rows only -> no block barrier needed)
#pragma unroll
    for (int ct = 0; ct < 8; ++ct)
#pragma unroll
      for (int r = 0; r < 4; ++r)
        *(unsigned short*)((char*)sS + swz(prow + r, ct * 16 + lr)) = f2bf(s[ct][r]);

    // 2) A fragments: row = wave*16 + lr, k = kt*32 + lg*8 .. +8 (contiguous b128)
    bf16x8 af[4];
#pragma unroll
    for (int kt = 0; kt < 4; ++kt)
      af[kt] = *(const bf16x8*)((char*)sS + swz(wave * MW + lr, kt * 32 + lg * 8));

    // 3) T = S @ Wh over 8 column tiles
    f32x4 acc[8];
#pragma unroll
    for (int ct = 0; ct < 8; ++ct) {
      acc[ct] = (f32x4){0.f, 0.f, 0.f, 0.f};
#pragma unroll
      for (int kt = 0; kt < 4; ++kt) {
        bf16x8 bf = *(const bf16x8*)((char*)whT + swz(ct * 16 + lr, kt * 32 + lg * 8));
        acc[ct] = __builtin_amdgcn_mfma_f32_16x16x32_bf16(af[kt], bf, acc[ct], 0, 0, 0);
      }
    }

    // 4) EM update in D layout (col = ct*16+lr, row = prow+r)
#pragma unroll
    for (int ct = 0; ct < 8; ++ct)
#pragma unroll
      for (int r = 0; r < 4; ++r) {
        float eps = noise[((size_t)(bk0 + prow + r) * NU + n) * H_ + ct * 16 + lr];
        float t  = tanh_fast(xwx_r[ct] + acc[ct][r]);
        float sv = s[ct][r];
        s[ct][r] = sv + (t - sv) * dt + gsd_r[ct] * eps;
      }
  }

  // write new particles (fp32)
#pragma unroll
  for (int ct = 0; ct < 8; ++ct)
#pragma unroll
    for (int r = 0; r < 4; ++r)
      p_out[(size_t)(bk0 + prow + r) * H_ + ct * 16 + lr] = s[ct][r];
}

// ---------------- resampling + weighted output kernel ----------------
__device__ __forceinline__ float blk_max(float v, float* red, int k){
  red[k]=v; __syncthreads();
  for (int off=128; off>0; off>>=1){ if (k<off) red[k]=fmaxf(red[k],red[k+off]); __syncthreads(); }
  float r = red[0]; __syncthreads(); return r;
}
__device__ __forceinline__ float blk_sum(float v, float* red, int k){
  red[k]=v; __syncthreads();
  for (int off=128; off>0; off>>=1){ if (k<off) red[k]+=red[k+off]; __syncthreads(); }
  float r = red[0]; __syncthreads(); return r;
}

// one block per batch, 256 threads = K particles
__global__ __launch_bounds__(256) void finish_kernel(
  const float* __restrict__ log_weights,   // [B,K]
  const float* __restrict__ resample_u,    // [B,K]
  const float* __restrict__ W_out,         // [H,O]
  const float* __restrict__ b_out,         // [O]
  const float* __restrict__ alpha_logit,   // [1]
  float* __restrict__ p,                   // [B*K,H] new particles (in d_out)
  float* __restrict__ out0,                // [B,O]
  float* __restrict__ lw_out)              // [B,K]
{
  const int b = blockIdx.x, k = threadIdx.x;
  __shared__ float red[K_];
  __shared__ float lw[K_], qv[K_], cdf[K_], wt[K_];
  __shared__ float ws_h[H_];

  float lwk = log_weights[b*K_ + k];
  float mx  = blk_max(lwk, red, k);
  float se  = blk_sum(expf(lwk - mx), red, k);
  float lse = mx + logf(se);
  float lwn = lwk - lse;
  lw[k] = lwn;
  float w = expf(lwn);
  float sw2 = blk_sum(w*w, red, k);
  float ess = 1.0f / sw2;

  float alpha = 1.0f/(1.0f + expf(-alpha_logit[0]));
  float qk = alpha*w + (1.0f-alpha)*(1.0f/K_);
  qv[k] = qk;
  cdf[k] = qk; __syncthreads();
  for (int off=1; off<K_; off<<=1){
    float add = (k>=off)? cdf[k-off] : 0.0f;
    __syncthreads();
    cdf[k] += add;
    __syncthreads();
  }
  float u = resample_u[b*K_ + k];
  int lo=0, cnt=K_;
  while (cnt>0){ int st=cnt>>1; if (cdf[lo+st] < u){ lo += st+1; cnt -= st+1; } else cnt = st; }
  int idx = min(lo, K_-1);

  float lr  = lw[idx] - logf(qv[idx]);
  float mx2 = blk_max(lr, red, k);
  float se2 = blk_sum(expf(lr-mx2), red, k);
  float lrn = lr - (mx2 + logf(se2));

  bool need = ess < 0.5f * K_;
  float flw = need ? lrn : lwn;
  lw_out[b*K_ + k] = flw;

  float mx3 = blk_max(flw, red, k);
  float se3 = blk_sum(expf(flw-mx3), red, k);
  float wk  = expf(flw - (mx3 + logf(se3)));
  wt[k] = wk;
  float sumw = blk_sum(wk, red, k);

  int h = k & (H_-1), half = k >> 7;
  float part = 0.f;
  const float* pb = &p[(size_t)b*K_*H_];
  for (int kk = half*128; kk < half*128 + 128; ++kk)
    part = fmaf(wt[kk], pb[(size_t)kk*H_ + h], part);
  red[k] = part; __syncthreads();
  if (k < H_) ws_h[k] = red[k] + red[k+H_];
  __syncthreads();

  if (k < O_) {
    float acc = sumw * b_out[k];
#pragma unroll 8
    for (int hh = 0; hh < H_; ++hh) acc = fmaf(ws_h[hh], W_out[hh*O_ + k], acc);
    out0[b*O_ + k] = acc;
  }

  if (need) {
    const float* src = &p[((size_t)b*K_ + idx)*H_];
    float* dstp      = &p[((size_t)b*K_ + k  )*H_];
    float tmp[16];
    for (int c = 0; c < H_; c += 16){
#pragma unroll
      for (int t=0;t<16;++t) tmp[t]=src[c+t];
      __syncthreads();
#pragma unroll
      for (int t=0;t<16;++t) dstp[c+t]=tmp[t];
      __syncthreads();
    }
  }
}

extern "C" void kernel_launch(void* const* d_in, const int* in_sizes, int n_in,
                              void* d_out, int out_size, void* d_ws, size_t ws_size,
                              hipStream_t stream) {
  const float* x           = (const float*)d_in[0];
  const float* particles   = (const float*)d_in[1];
  const float* log_weights = (const float*)d_in[2];
  const float* noise       = (const float*)d_in[3];
  const float* resample_u  = (const float*)d_in[4];
  const float* Wx          = (const float*)d_in[5];
  const float* Wh          = (const float*)d_in[6];
  const float* bvec        = (const float*)d_in[7];
  const float* log_sigma   = (const float*)d_in[8];
  const float* W_out       = (const float*)d_in[9];
  const float* b_out       = (const float*)d_in[10];
  const float* alpha_logit = (const float*)d_in[11];

  float* out0   = (float*)d_out;
  float* p_out  = out0 + B_*O_;
  float* lw_out = p_out + (size_t)B_*K_*H_;

  prop_kernel<<<(B_*K_)/BP, 256, 0, stream>>>(
      x, particles, noise, Wx, Wh, bvec, log_sigma, p_out);
  finish_kernel<<<B_, 256, 0, stream>>>(
      log_weights, resample_u, W_out, b_out, alpha_logit, p_out, out0, lw_out);
}